// Round 6
// baseline (310.305 us; speedup 1.0000x reference)
//
#include <hip/hip_runtime.h>
#include <hip/hip_bf16.h>

// MultiHeadedSelfAttention: B=4, S=2048, D=1024, H=16, W=64
//   1. cast x -> bf16 (scratch inside d_out, dead until final write)
//   2. cast Wq/Wk/Wv -> bf16; mask -> bf16 {0,1}
//   3. fused projection GEMM (q,k,v) -> head layouts in ws
//      q is PRESCALED by (1/8)*log2(e); q/k epilogues use swapped-operand
//      MFMA so stores pack bf16x4 along w; V masked-keys zeroed.
//   4. flash attention, 32x32 MFMA, swapped QK^T, in-register P exchange
//      (cvt_pk + permlane32_swap), row-sums via mask-vector MFMA,
//      XCD-aware block swizzle (all q-tiles of a head on one XCD).
// K/V LDS tiles XOR-swizzled (elem ^ ((row&7)<<3)) via pre-swizzled global
// source columns (global_load_lds writes linearly; same involution on read).

#define NB 4
#define NS 2048
#define ND 1024
#define NH 16
#define NW 64

typedef __bf16 bf16;
typedef __bf16 bf16x2 __attribute__((ext_vector_type(2)));
typedef __bf16 bf16x4 __attribute__((ext_vector_type(4)));
typedef __bf16 bf16x8 __attribute__((ext_vector_type(8)));
typedef float f32x4 __attribute__((ext_vector_type(4)));
typedef float f32x16 __attribute__((ext_vector_type(16)));
typedef unsigned u32x4 __attribute__((ext_vector_type(4)));

__device__ __forceinline__ void gld_lds16(const void* g, void* l) {
  __builtin_amdgcn_global_load_lds(
      (const __attribute__((address_space(1))) void*)g,
      (__attribute__((address_space(3))) void*)l, 16, 0, 0);
}

__device__ __forceinline__ unsigned pack2(float lo, float hi) {
  bf16x2 t;
  t[0] = (bf16)lo;
  t[1] = (bf16)hi;
  return __builtin_bit_cast(unsigned, t);
}

__global__ void cast_f32_bf16(const float* __restrict__ src,
                              bf16* __restrict__ dst, int n) {
  int i = (blockIdx.x * blockDim.x + threadIdx.x) * 8;
  int stride = gridDim.x * blockDim.x * 8;
  for (; i < n; i += stride) {
    float4 a = *reinterpret_cast<const float4*>(src + i);
    float4 b = *reinterpret_cast<const float4*>(src + i + 4);
    bf16x8 o;
    o[0] = (bf16)a.x; o[1] = (bf16)a.y; o[2] = (bf16)a.z; o[3] = (bf16)a.w;
    o[4] = (bf16)b.x; o[5] = (bf16)b.y; o[6] = (bf16)b.z; o[7] = (bf16)b.w;
    *reinterpret_cast<bf16x8*>(dst + i) = o;
  }
}

__global__ void cast_weights(const float* __restrict__ a,
                             const float* __restrict__ b,
                             const float* __restrict__ c,
                             bf16* __restrict__ dst) {
  const int n = ND * ND;
  const int which = blockIdx.y;
  const float* src = (which == 0) ? a : ((which == 1) ? b : c);
  bf16* d = dst + (size_t)which * n;
  int i = (blockIdx.x * blockDim.x + threadIdx.x) * 8;
  float4 u = *reinterpret_cast<const float4*>(src + i);
  float4 v = *reinterpret_cast<const float4*>(src + i + 4);
  bf16x8 o;
  o[0] = (bf16)u.x; o[1] = (bf16)u.y; o[2] = (bf16)u.z; o[3] = (bf16)u.w;
  o[4] = (bf16)v.x; o[5] = (bf16)v.y; o[6] = (bf16)v.z; o[7] = (bf16)v.w;
  *reinterpret_cast<bf16x8*>(d + i) = o;
}

__global__ void mask_to_bf16(const int* __restrict__ mask,
                             bf16* __restrict__ mb, int n) {
  int i = blockIdx.x * blockDim.x + threadIdx.x;
  if (i < n) mb[i] = (bf16)(mask[i] ? 1.0f : 0.0f);
}

// ---------------- projection GEMM ----------------
__global__ __launch_bounds__(256) void proj_kernel(
    const bf16* __restrict__ xb,
    const bf16* __restrict__ wq,
    const bf16* __restrict__ wk,
    const bf16* __restrict__ wv,
    const float* __restrict__ bq,
    const float* __restrict__ bk,
    const float* __restrict__ bv,
    const int* __restrict__ mask,
    bf16* __restrict__ qh,
    bf16* __restrict__ kh,
    bf16* __restrict__ vt) {
  const int mode = blockIdx.z;
  const bf16* wmat = (mode == 0) ? wq : ((mode == 1) ? wk : wv);
  const float* bias = (mode == 0) ? bq : ((mode == 1) ? bk : bv);

  __shared__ alignas(16) bf16 a_lds[128][64];
  __shared__ alignas(16) bf16 b_lds[128][64];

  const int tid = threadIdx.x;
  const int wave = tid >> 6;
  const int lane = tid & 63;
  const int wr = wave >> 1, wc = wave & 1;
  const int m0 = blockIdx.x * 128;
  const int n0 = blockIdx.y * 128;

  f32x4 acc[4][4] = {};

  const int srow = tid >> 3;
  const int scol = (tid & 7) * 8;
  const int sw_scol = scol ^ ((srow & 7) << 3);
  const int xr = (lane & 7) << 3;
  const int lr = lane & 15;
  const int g = lane >> 4;
  const int kq = g * 8;

  for (int k0 = 0; k0 < 1024; k0 += 64) {
#pragma unroll
    for (int c = 0; c < 4; ++c) {
      int row = srow + c * 32;
      gld_lds16(xb + (size_t)(m0 + row) * 1024 + k0 + sw_scol, &a_lds[row][scol]);
      gld_lds16(wmat + (size_t)(n0 + row) * 1024 + k0 + sw_scol, &b_lds[row][scol]);
    }
    __syncthreads();
#pragma unroll
    for (int kk = 0; kk < 64; kk += 32) {
      bf16x8 af[4], bfr[4];
      const int col = (kk + kq) ^ xr;
#pragma unroll
      for (int mf = 0; mf < 4; ++mf)
        af[mf] = *reinterpret_cast<const bf16x8*>(&a_lds[wr * 64 + mf * 16 + lr][col]);
#pragma unroll
      for (int nf = 0; nf < 4; ++nf)
        bfr[nf] = *reinterpret_cast<const bf16x8*>(&b_lds[wc * 64 + nf * 16 + lr][col]);
      if (mode == 2) {
        // normal: D reg-rows = x-rows (s), lane-cols = W-rows (j)
#pragma unroll
        for (int mf = 0; mf < 4; ++mf)
#pragma unroll
          for (int nf = 0; nf < 4; ++nf)
            acc[mf][nf] = __builtin_amdgcn_mfma_f32_16x16x32_bf16(af[mf], bfr[nf], acc[mf][nf], 0, 0, 0);
      } else {
        // swapped: D reg-rows = W-rows (j/w), lane-cols = x-rows (s)
#pragma unroll
        for (int nf = 0; nf < 4; ++nf)
#pragma unroll
          for (int mf = 0; mf < 4; ++mf)
            acc[nf][mf] = __builtin_amdgcn_mfma_f32_16x16x32_bf16(bfr[nf], af[mf], acc[nf][mf], 0, 0, 0);
      }
    }
    __syncthreads();
  }

  if (mode == 2) {
    // V^T per head, masked keys zeroed; pack along s
    float msk[4][4];
#pragma unroll
    for (int mf = 0; mf < 4; ++mf) {
      const int i0 = m0 + wr * 64 + mf * 16 + g * 4;
      const int b = i0 >> 11, s = i0 & 2047;
      const int4 mm = *reinterpret_cast<const int4*>(mask + b * NS + s);
      msk[mf][0] = mm.x ? 1.f : 0.f;
      msk[mf][1] = mm.y ? 1.f : 0.f;
      msk[mf][2] = mm.z ? 1.f : 0.f;
      msk[mf][3] = mm.w ? 1.f : 0.f;
    }
#pragma unroll
    for (int nf = 0; nf < 4; ++nf) {
      const int j = n0 + wc * 64 + nf * 16 + lr;
      const float bj = bias[j];
      const int h = j >> 6, w = j & 63;
#pragma unroll
      for (int mf = 0; mf < 4; ++mf) {
        const int i0 = m0 + wr * 64 + mf * 16 + g * 4;
        const int b = i0 >> 11, s = i0 & 2047;
        bf16x4 pk;
#pragma unroll
        for (int r = 0; r < 4; ++r)
          pk[r] = (bf16)((acc[mf][nf][r] + bj) * msk[mf][r]);
        *reinterpret_cast<bf16x4*>(&vt[(((size_t)(b * NH + h)) * NW + w) * NS + s]) = pk;
      }
    }
  } else {
    // q/k: pack along w; q prescaled by (1/8)*log2(e)
    bf16* dst = (mode == 0) ? qh : kh;
    const float scl = (mode == 0) ? 0.18033688011112042f : 1.0f;
#pragma unroll
    for (int nf = 0; nf < 4; ++nf) {
      const int j0 = n0 + wc * 64 + nf * 16 + g * 4;
      const f32x4 bj = *reinterpret_cast<const f32x4*>(&bias[j0]);
      const int h = j0 >> 6, w0 = j0 & 63;
#pragma unroll
      for (int mf = 0; mf < 4; ++mf) {
        const int i = m0 + wr * 64 + mf * 16 + lr;
        const int b = i >> 11, s = i & 2047;
        bf16x4 pk;
#pragma unroll
        for (int r = 0; r < 4; ++r)
          pk[r] = (bf16)((acc[nf][mf][r] + bj[r]) * scl);
        *reinterpret_cast<bf16x4*>(&dst[(((size_t)(b * NH + h)) * NS + s) * NW + w0]) = pk;
      }
    }
  }
}

// ---------------- flash attention ----------------
// grid: 1024 linear blocks, XCD-swizzled: all 16 q-tiles of a head (2 heads)
// land on one XCD so K/V stay in its L2. 4 waves, 32 q-rows/wave, 32x32 MFMA.
__global__ __launch_bounds__(256, 4) void attn_kernel(
    const bf16* __restrict__ qh,
    const bf16* __restrict__ kh,
    const bf16* __restrict__ vt,
    const bf16* __restrict__ mb16,
    float* __restrict__ out) {
  __shared__ alignas(16) bf16 k_lds[2][64][64];
  __shared__ alignas(16) bf16 v_lds[2][64][64];  // [w][t]

  const int tid = threadIdx.x;
  const int wave = tid >> 6;
  const int lane = tid & 63;
  const int lq = lane & 31;
  const int hi = lane >> 5;
  const int xr = (lq & 7) << 3;

  // XCD swizzle: physical id p -> work w = (p%8)*128 + p/8
  const int p = blockIdx.x;
  const int w_id = (p & 7) * 128 + (p >> 3);
  const int bh = w_id >> 4;
  const int b = bh >> 4;
  const int q0 = (w_id & 15) * 128;
  const size_t headoff = (size_t)bh * NS * NW;

  // Q fragments (B operand), prescaled in proj
  bf16x8 qf[4];
  {
    const bf16* qp = qh + headoff + (size_t)(q0 + wave * 32 + lq) * NW + hi * 8;
#pragma unroll
    for (int m = 0; m < 4; ++m)
      qf[m] = *reinterpret_cast<const bf16x8*>(qp + m * 16);
  }

  f32x16 o0 = {}, o1 = {}, lt = {};
  const bf16* mp = mb16 + b * NS;

  const int srow = tid >> 3;
  const int scol = (tid & 7) * 8;
  const int sw_scol = scol ^ ((srow & 7) << 3);

#define STAGE(buf, kt)                                                          \
  {                                                                             \
    _Pragma("unroll") for (int c = 0; c < 2; ++c) {                             \
      const int row = srow + c * 32;                                            \
      gld_lds16(kh + headoff + (size_t)((kt) + row) * NW + sw_scol,             \
                &k_lds[buf][row][scol]);                                        \
      gld_lds16(vt + headoff + (size_t)row * NS + (kt) + sw_scol,               \
                &v_lds[buf][row][scol]);                                        \
    }                                                                           \
  }

  // exp + pack one group's scores into two PV A-fragments
#define EXPPACK(S, PA0, PA1)                                                    \
  {                                                                             \
    unsigned w_[8];                                                             \
    _Pragma("unroll") for (int j = 0; j < 8; ++j)                               \
        w_[j] = pack2(exp2f(S[2 * j]), exp2f(S[2 * j + 1]));                    \
    asm("v_permlane32_swap_b32 %0, %1" : "+v"(w_[0]), "+v"(w_[2]));             \
    asm("v_permlane32_swap_b32 %0, %1" : "+v"(w_[1]), "+v"(w_[3]));             \
    asm("v_permlane32_swap_b32 %0, %1" : "+v"(w_[4]), "+v"(w_[6]));             \
    asm("v_permlane32_swap_b32 %0, %1" : "+v"(w_[5]), "+v"(w_[7]));             \
    u32x4 u0 = {w_[0], w_[1], w_[2], w_[3]};                                    \
    u32x4 u1 = {w_[4], w_[5], w_[6], w_[7]};                                    \
    PA0 = __builtin_bit_cast(bf16x8, u0);                                       \
    PA1 = __builtin_bit_cast(bf16x8, u1);                                       \
  }

  STAGE(0, 0);
  __syncthreads();

  int cur = 0;
  for (int kt = 0; kt < NS; kt += 64) {
    if (kt + 64 < NS) STAGE(cur ^ 1, kt + 64);

    // ---- QK^T: both 32-key groups, two independent MFMA chains ----
    f32x16 s0 = {}, s1 = {};
    __builtin_amdgcn_s_setprio(1);
#pragma unroll
    for (int m = 0; m < 4; ++m) {
      const int col = (m * 16 + hi * 8) ^ xr;
      bf16x8 kf0 = *reinterpret_cast<const bf16x8*>(&k_lds[cur][lq][col]);
      s0 = __builtin_amdgcn_mfma_f32_32x32x16_bf16(kf0, qf[m], s0, 0, 0, 0);
      bf16x8 kf1 = *reinterpret_cast<const bf16x8*>(&k_lds[cur][32 + lq][col]);
      s1 = __builtin_amdgcn_mfma_f32_32x32x16_bf16(kf1, qf[m], s1, 0, 0, 0);
    }
    __builtin_amdgcn_s_setprio(0);

    // ---- softmax numerators, in-register ----
    bf16x8 pa0, pa1, pa2, pa3;
    EXPPACK(s0, pa0, pa1);
    EXPPACK(s1, pa2, pa3);

    // mask fragments (L1-broadcast)
    const bf16* mpk = mp + kt + hi * 8;
    bf16x8 mf00 = *reinterpret_cast<const bf16x8*>(mpk);
    bf16x8 mf01 = *reinterpret_cast<const bf16x8*>(mpk + 16);
    bf16x8 mf10 = *reinterpret_cast<const bf16x8*>(mpk + 32);
    bf16x8 mf11 = *reinterpret_cast<const bf16x8*>(mpk + 48);

    // ---- PV + row-sums: 12 MFMA, 3 independent accumulator chains ----
    __builtin_amdgcn_s_setprio(1);
    lt = __builtin_amdgcn_mfma_f32_32x32x16_bf16(pa0, mf00, lt, 0, 0, 0);
    lt = __builtin_amdgcn_mfma_f32_32x32x16_bf16(pa1, mf01, lt, 0, 0, 0);
    lt = __builtin_amdgcn_mfma_f32_32x32x16_bf16(pa2, mf10, lt, 0, 0, 0);
    lt = __builtin_amdgcn_mfma_f32_32x32x16_bf16(pa3, mf11, lt, 0, 0, 0);
#pragma unroll
    for (int G = 0; G < 2; ++G) {
      const bf16x8 a0 = G ? pa2 : pa0;
      const bf16x8 a1 = G ? pa3 : pa1;
      const int c0 = (G * 32 + hi * 8) ^ xr;
      const int c1 = (G * 32 + 16 + hi * 8) ^ xr;
      bf16x8 v00 = *reinterpret_cast<const bf16x8*>(&v_lds[cur][lq][c0]);
      o0 = __builtin_amdgcn_mfma_f32_32x32x16_bf16(a0, v00, o0, 0, 0, 0);
      bf16x8 v01 = *reinterpret_cast<const bf16x8*>(&v_lds[cur][lq][c1]);
      o0 = __builtin_amdgcn_mfma_f32_32x32x16_bf16(a1, v01, o0, 0, 0, 0);
      bf16x8 v10 = *reinterpret_cast<const bf16x8*>(&v_lds[cur][32 + lq][c0]);
      o1 = __builtin_amdgcn_mfma_f32_32x32x16_bf16(a0, v10, o1, 0, 0, 0);
      bf16x8 v11 = *reinterpret_cast<const bf16x8*>(&v_lds[cur][32 + lq][c1]);
      o1 = __builtin_amdgcn_mfma_f32_32x32x16_bf16(a1, v11, o1, 0, 0, 0);
    }
    __builtin_amdgcn_s_setprio(0);

    __syncthreads();
    cur ^= 1;
  }

  // out[b][s][h*64+w] = o / l ; D rows: (r&3)+8*(r>>2)+4*hi, col lq
  const int h = bh & 15;
  float* op = out + ((size_t)b * NS) * ND + h * NW;
#pragma unroll
  for (int r = 0; r < 16; ++r) {
    const int sq = q0 + wave * 32 + (r & 3) + 8 * (r >> 2) + 4 * hi;
    const float inv = 1.0f / lt[r];
    op[(size_t)sq * ND + lq] = o0[r] * inv;
    op[(size_t)sq * ND + 32 + lq] = o1[r] * inv;
  }
#undef STAGE
#undef EXPPACK
}

extern "C" void kernel_launch(void* const* d_in, const int* in_sizes, int n_in,
                              void* d_out, int out_size, void* d_ws, size_t ws_size,
                              hipStream_t stream) {
  const float* x = (const float*)d_in[0];
  const int* mask = (const int*)d_in[1];
  const float* Wq = (const float*)d_in[2];
  const float* bq = (const float*)d_in[3];
  const float* Wk = (const float*)d_in[4];
  const float* bk = (const float*)d_in[5];
  const float* Wv = (const float*)d_in[6];
  const float* bv = (const float*)d_in[7];
  float* out = (float*)d_out;

  char* ws = (char*)d_ws;
  bf16* wqb = (bf16*)(ws + (size_t)(0) * (1 << 20));
  bf16* wkb = (bf16*)(ws + (size_t)(2) * (1 << 20));
  bf16* wvb = (bf16*)(ws + (size_t)(4) * (1 << 20));
  bf16* qhb = (bf16*)(ws + (size_t)(6) * (1 << 20));   // 16MB
  bf16* khb = (bf16*)(ws + (size_t)(22) * (1 << 20));  // 16MB
  bf16* vtb = (bf16*)(ws + (size_t)(38) * (1 << 20));  // 16MB
  bf16* mb16 = (bf16*)(ws + (size_t)(54) * (1 << 20)); // 16KB
  // bf16 copy of x lives in d_out's first 16MB (dead until attn writes)
  bf16* xb = (bf16*)d_out;

  cast_f32_bf16<<<2048, 256, 0, stream>>>(x, xb, NB * NS * ND);
  cast_weights<<<dim3(512, 3), 256, 0, stream>>>(Wq, Wk, Wv, wqb);
  mask_to_bf16<<<32, 256, 0, stream>>>(mask, mb16, NB * NS);
  proj_kernel<<<dim3(64, 8, 3), 256, 0, stream>>>(xb, wqb, wkb, wvb, bq, bk, bv,
                                                  mask, qhb, khb, vtb);
  attn_kernel<<<1024, 256, 0, stream>>>(qhb, khb, vtb, mb16, out);
}

// Round 7
// 281.574 us; speedup vs baseline: 1.1020x; 1.1020x over previous
//
#include <hip/hip_runtime.h>
#include <hip/hip_bf16.h>

// MultiHeadedSelfAttention: B=4, S=2048, D=1024, H=16, W=64
//   1. cast x -> bf16 (scratch inside d_out, dead until final write)
//   2. cast Wq/Wk/Wv -> bf16; mask -> bf16 {0,1}
//   3. projection GEMMs (template<MODE>, one launch each): 128x128 tile,
//      double-buffered LDS, XCD+L2-aware block mapping (each XCD owns a
//      2MB A-chunk; 8 concurrent blocks share each B-panel in L2).
//      q PRESCALED by (1/8)*log2(e); q/k use swapped-operand MFMA so
//      stores pack bf16x4 along w; V masked-keys zeroed.
//   4. flash attention, 32x32 MFMA, swapped QK^T, in-register P exchange
//      (cvt_pk + permlane32_swap), row-sums via mask-vector MFMA,
//      XCD-aware block swizzle. (unchanged from round 6: 117us measured)
// K/V LDS tiles XOR-swizzled (elem ^ ((row&7)<<3)) via pre-swizzled global
// source columns (global_load_lds writes linearly; same involution on read).

#define NB 4
#define NS 2048
#define ND 1024
#define NH 16
#define NW 64

typedef __bf16 bf16;
typedef __bf16 bf16x2 __attribute__((ext_vector_type(2)));
typedef __bf16 bf16x4 __attribute__((ext_vector_type(4)));
typedef __bf16 bf16x8 __attribute__((ext_vector_type(8)));
typedef float f32x4 __attribute__((ext_vector_type(4)));
typedef float f32x16 __attribute__((ext_vector_type(16)));
typedef unsigned u32x4 __attribute__((ext_vector_type(4)));

__device__ __forceinline__ void gld_lds16(const void* g, void* l) {
  __builtin_amdgcn_global_load_lds(
      (const __attribute__((address_space(1))) void*)g,
      (__attribute__((address_space(3))) void*)l, 16, 0, 0);
}

__device__ __forceinline__ unsigned pack2(float lo, float hi) {
  bf16x2 t;
  t[0] = (bf16)lo;
  t[1] = (bf16)hi;
  return __builtin_bit_cast(unsigned, t);
}

__global__ void cast_f32_bf16(const float* __restrict__ src,
                              bf16* __restrict__ dst, int n) {
  int i = (blockIdx.x * blockDim.x + threadIdx.x) * 8;
  int stride = gridDim.x * blockDim.x * 8;
  for (; i < n; i += stride) {
    float4 a = *reinterpret_cast<const float4*>(src + i);
    float4 b = *reinterpret_cast<const float4*>(src + i + 4);
    bf16x8 o;
    o[0] = (bf16)a.x; o[1] = (bf16)a.y; o[2] = (bf16)a.z; o[3] = (bf16)a.w;
    o[4] = (bf16)b.x; o[5] = (bf16)b.y; o[6] = (bf16)b.z; o[7] = (bf16)b.w;
    *reinterpret_cast<bf16x8*>(dst + i) = o;
  }
}

__global__ void cast_weights(const float* __restrict__ a,
                             const float* __restrict__ b,
                             const float* __restrict__ c,
                             bf16* __restrict__ dst) {
  const int n = ND * ND;
  const int which = blockIdx.y;
  const float* src = (which == 0) ? a : ((which == 1) ? b : c);
  bf16* d = dst + (size_t)which * n;
  int i = (blockIdx.x * blockDim.x + threadIdx.x) * 8;
  float4 u = *reinterpret_cast<const float4*>(src + i);
  float4 v = *reinterpret_cast<const float4*>(src + i + 4);
  bf16x8 o;
  o[0] = (bf16)u.x; o[1] = (bf16)u.y; o[2] = (bf16)u.z; o[3] = (bf16)u.w;
  o[4] = (bf16)v.x; o[5] = (bf16)v.y; o[6] = (bf16)v.z; o[7] = (bf16)v.w;
  *reinterpret_cast<bf16x8*>(d + i) = o;
}

__global__ void mask_to_bf16(const int* __restrict__ mask,
                             bf16* __restrict__ mb, int n) {
  int i = blockIdx.x * blockDim.x + threadIdx.x;
  if (i < n) mb[i] = (bf16)(mask[i] ? 1.0f : 0.0f);
}

// ---------------- projection GEMM ----------------
// MODE: 0 = q (prescaled, pack along w), 1 = k (pack along w),
//       2 = v (transposed per head, masked keys zeroed, pack along s)
template <int MODE>
__global__ __launch_bounds__(256) void proj_kernel(
    const bf16* __restrict__ xb,
    const bf16* __restrict__ wmat,
    const float* __restrict__ bias,
    const int* __restrict__ mask,
    bf16* __restrict__ dst) {
  __shared__ alignas(16) bf16 a_lds[2][128][64];
  __shared__ alignas(16) bf16 b_lds[2][128][64];

  const int tid = threadIdx.x;
  const int wave = tid >> 6;
  const int lane = tid & 63;
  const int wr = wave >> 1, wc = wave & 1;

  // XCD+L2-aware mapping: p -> xcd=p&7, q=p>>3; m-fastest within xcd chunk
  const int p = blockIdx.x;
  const int xcd = p & 7, q = p >> 3;
  const int m0 = (xcd * 8 + (q & 7)) * 128;  // 8 m-blocks per XCD chunk
  const int n0 = (q >> 3) * 128;             // 8 n-blocks

  f32x4 acc[4][4] = {};

  const int srow = tid >> 3;
  const int scol = (tid & 7) * 8;
  const int sw_scol = scol ^ ((srow & 7) << 3);
  const int xr = (lane & 7) << 3;
  const int lr = lane & 15;
  const int g = lane >> 4;
  const int kq = g * 8;

#define PSTAGE(buf, k0)                                                         \
  {                                                                             \
    _Pragma("unroll") for (int c = 0; c < 4; ++c) {                             \
      const int row = srow + c * 32;                                            \
      gld_lds16(xb + (size_t)(m0 + row) * 1024 + (k0) + sw_scol,                \
                &a_lds[buf][row][scol]);                                        \
      gld_lds16(wmat + (size_t)(n0 + row) * 1024 + (k0) + sw_scol,              \
                &b_lds[buf][row][scol]);                                        \
    }                                                                           \
  }

  PSTAGE(0, 0);
  __syncthreads();

  int cur = 0;
  for (int k0 = 0; k0 < 1024; k0 += 64) {
    if (k0 + 64 < 1024) PSTAGE(cur ^ 1, k0 + 64);
#pragma unroll
    for (int kk = 0; kk < 64; kk += 32) {
      bf16x8 af[4], bfr[4];
      const int col = (kk + kq) ^ xr;
#pragma unroll
      for (int mf = 0; mf < 4; ++mf)
        af[mf] = *reinterpret_cast<const bf16x8*>(&a_lds[cur][wr * 64 + mf * 16 + lr][col]);
#pragma unroll
      for (int nf = 0; nf < 4; ++nf)
        bfr[nf] = *reinterpret_cast<const bf16x8*>(&b_lds[cur][wc * 64 + nf * 16 + lr][col]);
      if (MODE == 2) {
        // normal: D reg-rows = x-rows (s), lane-cols = W-rows (j)
#pragma unroll
        for (int mf = 0; mf < 4; ++mf)
#pragma unroll
          for (int nf = 0; nf < 4; ++nf)
            acc[mf][nf] = __builtin_amdgcn_mfma_f32_16x16x32_bf16(af[mf], bfr[nf], acc[mf][nf], 0, 0, 0);
      } else {
        // swapped: D reg-rows = W-rows (j/w), lane-cols = x-rows (s)
#pragma unroll
        for (int nf = 0; nf < 4; ++nf)
#pragma unroll
          for (int mf = 0; mf < 4; ++mf)
            acc[nf][mf] = __builtin_amdgcn_mfma_f32_16x16x32_bf16(bfr[nf], af[mf], acc[nf][mf], 0, 0, 0);
      }
    }
    __syncthreads();
    cur ^= 1;
  }

  if (MODE == 2) {
    // V^T per head, masked keys zeroed; pack along s
    float msk[4][4];
#pragma unroll
    for (int mf = 0; mf < 4; ++mf) {
      const int i0 = m0 + wr * 64 + mf * 16 + g * 4;
      const int b = i0 >> 11, s = i0 & 2047;
      const int4 mm = *reinterpret_cast<const int4*>(mask + b * NS + s);
      msk[mf][0] = mm.x ? 1.f : 0.f;
      msk[mf][1] = mm.y ? 1.f : 0.f;
      msk[mf][2] = mm.z ? 1.f : 0.f;
      msk[mf][3] = mm.w ? 1.f : 0.f;
    }
#pragma unroll
    for (int nf = 0; nf < 4; ++nf) {
      const int j = n0 + wc * 64 + nf * 16 + lr;
      const float bj = bias[j];
      const int h = j >> 6, w = j & 63;
#pragma unroll
      for (int mf = 0; mf < 4; ++mf) {
        const int i0 = m0 + wr * 64 + mf * 16 + g * 4;
        const int b = i0 >> 11, s = i0 & 2047;
        bf16x4 pk;
#pragma unroll
        for (int r = 0; r < 4; ++r)
          pk[r] = (bf16)((acc[mf][nf][r] + bj) * msk[mf][r]);
        *reinterpret_cast<bf16x4*>(&dst[(((size_t)(b * NH + h)) * NW + w) * NS + s]) = pk;
      }
    }
  } else {
    // q/k: pack along w; q prescaled by (1/8)*log2(e)
    const float scl = (MODE == 0) ? 0.18033688011112042f : 1.0f;
#pragma unroll
    for (int nf = 0; nf < 4; ++nf) {
      const int j0 = n0 + wc * 64 + nf * 16 + g * 4;
      const f32x4 bj = *reinterpret_cast<const f32x4*>(&bias[j0]);
      const int h = j0 >> 6, w0 = j0 & 63;
#pragma unroll
      for (int mf = 0; mf < 4; ++mf) {
        const int i = m0 + wr * 64 + mf * 16 + lr;
        const int b = i >> 11, s = i & 2047;
        bf16x4 pk;
#pragma unroll
        for (int r = 0; r < 4; ++r)
          pk[r] = (bf16)((acc[nf][mf][r] + bj[r]) * scl);
        *reinterpret_cast<bf16x4*>(&dst[(((size_t)(b * NH + h)) * NS + s) * NW + w0]) = pk;
      }
    }
  }
#undef PSTAGE
}

// ---------------- flash attention ----------------
// grid: 1024 linear blocks, XCD-swizzled: all 16 q-tiles of a head (8 heads
// per XCD) land on one XCD so K/V stay in its L2. 4 waves, 32 q-rows/wave.
__global__ __launch_bounds__(256, 4) void attn_kernel(
    const bf16* __restrict__ qh,
    const bf16* __restrict__ kh,
    const bf16* __restrict__ vt,
    const bf16* __restrict__ mb16,
    float* __restrict__ out) {
  __shared__ alignas(16) bf16 k_lds[2][64][64];
  __shared__ alignas(16) bf16 v_lds[2][64][64];  // [w][t]

  const int tid = threadIdx.x;
  const int wave = tid >> 6;
  const int lane = tid & 63;
  const int lq = lane & 31;
  const int hi = lane >> 5;
  const int xr = (lq & 7) << 3;

  const int p = blockIdx.x;
  const int w_id = (p & 7) * 128 + (p >> 3);
  const int bh = w_id >> 4;
  const int b = bh >> 4;
  const int q0 = (w_id & 15) * 128;
  const size_t headoff = (size_t)bh * NS * NW;

  bf16x8 qf[4];
  {
    const bf16* qp = qh + headoff + (size_t)(q0 + wave * 32 + lq) * NW + hi * 8;
#pragma unroll
    for (int m = 0; m < 4; ++m)
      qf[m] = *reinterpret_cast<const bf16x8*>(qp + m * 16);
  }

  f32x16 o0 = {}, o1 = {}, lt = {};
  const bf16* mp = mb16 + b * NS;

  const int srow = tid >> 3;
  const int scol = (tid & 7) * 8;
  const int sw_scol = scol ^ ((srow & 7) << 3);

#define STAGE(buf, kt)                                                          \
  {                                                                             \
    _Pragma("unroll") for (int c = 0; c < 2; ++c) {                             \
      const int row = srow + c * 32;                                            \
      gld_lds16(kh + headoff + (size_t)((kt) + row) * NW + sw_scol,             \
                &k_lds[buf][row][scol]);                                        \
      gld_lds16(vt + headoff + (size_t)row * NS + (kt) + sw_scol,               \
                &v_lds[buf][row][scol]);                                        \
    }                                                                           \
  }

#define EXPPACK(S, PA0, PA1)                                                    \
  {                                                                             \
    unsigned w_[8];                                                             \
    _Pragma("unroll") for (int j = 0; j < 8; ++j)                               \
        w_[j] = pack2(exp2f(S[2 * j]), exp2f(S[2 * j + 1]));                    \
    asm("v_permlane32_swap_b32 %0, %1" : "+v"(w_[0]), "+v"(w_[2]));             \
    asm("v_permlane32_swap_b32 %0, %1" : "+v"(w_[1]), "+v"(w_[3]));             \
    asm("v_permlane32_swap_b32 %0, %1" : "+v"(w_[4]), "+v"(w_[6]));             \
    asm("v_permlane32_swap_b32 %0, %1" : "+v"(w_[5]), "+v"(w_[7]));             \
    u32x4 u0 = {w_[0], w_[1], w_[2], w_[3]};                                    \
    u32x4 u1 = {w_[4], w_[5], w_[6], w_[7]};                                    \
    PA0 = __builtin_bit_cast(bf16x8, u0);                                       \
    PA1 = __builtin_bit_cast(bf16x8, u1);                                       \
  }

  STAGE(0, 0);
  __syncthreads();

  int cur = 0;
  for (int kt = 0; kt < NS; kt += 64) {
    if (kt + 64 < NS) STAGE(cur ^ 1, kt + 64);

    f32x16 s0 = {}, s1 = {};
    __builtin_amdgcn_s_setprio(1);
#pragma unroll
    for (int m = 0; m < 4; ++m) {
      const int col = (m * 16 + hi * 8) ^ xr;
      bf16x8 kf0 = *reinterpret_cast<const bf16x8*>(&k_lds[cur][lq][col]);
      s0 = __builtin_amdgcn_mfma_f32_32x32x16_bf16(kf0, qf[m], s0, 0, 0, 0);
      bf16x8 kf1 = *reinterpret_cast<const bf16x8*>(&k_lds[cur][32 + lq][col]);
      s1 = __builtin_amdgcn_mfma_f32_32x32x16_bf16(kf1, qf[m], s1, 0, 0, 0);
    }
    __builtin_amdgcn_s_setprio(0);

    bf16x8 pa0, pa1, pa2, pa3;
    EXPPACK(s0, pa0, pa1);
    EXPPACK(s1, pa2, pa3);

    const bf16* mpk = mp + kt + hi * 8;
    bf16x8 mf00 = *reinterpret_cast<const bf16x8*>(mpk);
    bf16x8 mf01 = *reinterpret_cast<const bf16x8*>(mpk + 16);
    bf16x8 mf10 = *reinterpret_cast<const bf16x8*>(mpk + 32);
    bf16x8 mf11 = *reinterpret_cast<const bf16x8*>(mpk + 48);

    __builtin_amdgcn_s_setprio(1);
    lt = __builtin_amdgcn_mfma_f32_32x32x16_bf16(pa0, mf00, lt, 0, 0, 0);
    lt = __builtin_amdgcn_mfma_f32_32x32x16_bf16(pa1, mf01, lt, 0, 0, 0);
    lt = __builtin_amdgcn_mfma_f32_32x32x16_bf16(pa2, mf10, lt, 0, 0, 0);
    lt = __builtin_amdgcn_mfma_f32_32x32x16_bf16(pa3, mf11, lt, 0, 0, 0);
#pragma unroll
    for (int G = 0; G < 2; ++G) {
      const bf16x8 a0 = G ? pa2 : pa0;
      const bf16x8 a1 = G ? pa3 : pa1;
      const int c0 = (G * 32 + hi * 8) ^ xr;
      const int c1 = (G * 32 + 16 + hi * 8) ^ xr;
      bf16x8 v00 = *reinterpret_cast<const bf16x8*>(&v_lds[cur][lq][c0]);
      o0 = __builtin_amdgcn_mfma_f32_32x32x16_bf16(a0, v00, o0, 0, 0, 0);
      bf16x8 v01 = *reinterpret_cast<const bf16x8*>(&v_lds[cur][lq][c1]);
      o0 = __builtin_amdgcn_mfma_f32_32x32x16_bf16(a1, v01, o0, 0, 0, 0);
      bf16x8 v10 = *reinterpret_cast<const bf16x8*>(&v_lds[cur][32 + lq][c0]);
      o1 = __builtin_amdgcn_mfma_f32_32x32x16_bf16(a0, v10, o1, 0, 0, 0);
      bf16x8 v11 = *reinterpret_cast<const bf16x8*>(&v_lds[cur][32 + lq][c1]);
      o1 = __builtin_amdgcn_mfma_f32_32x32x16_bf16(a1, v11, o1, 0, 0, 0);
    }
    __builtin_amdgcn_s_setprio(0);

    __syncthreads();
    cur ^= 1;
  }

  const int h = bh & 15;
  float* op = out + ((size_t)b * NS) * ND + h * NW;
#pragma unroll
  for (int r = 0; r < 16; ++r) {
    const int sq = q0 + wave * 32 + (r & 3) + 8 * (r >> 2) + 4 * hi;
    const float inv = 1.0f / lt[r];
    op[(size_t)sq * ND + lq] = o0[r] * inv;
    op[(size_t)sq * ND + 32 + lq] = o1[r] * inv;
  }
#undef STAGE
#undef EXPPACK
}

extern "C" void kernel_launch(void* const* d_in, const int* in_sizes, int n_in,
                              void* d_out, int out_size, void* d_ws, size_t ws_size,
                              hipStream_t stream) {
  const float* x = (const float*)d_in[0];
  const int* mask = (const int*)d_in[1];
  const float* Wq = (const float*)d_in[2];
  const float* bq = (const float*)d_in[3];
  const float* Wk = (const float*)d_in[4];
  const float* bk = (const float*)d_in[5];
  const float* Wv = (const float*)d_in[6];
  const float* bv = (const float*)d_in[7];
  float* out = (float*)d_out;

  char* ws = (char*)d_ws;
  bf16* wqb = (bf16*)(ws + (size_t)(0) * (1 << 20));
  bf16* wkb = (bf16*)(ws + (size_t)(2) * (1 << 20));
  bf16* wvb = (bf16*)(ws + (size_t)(4) * (1 << 20));
  bf16* qhb = (bf16*)(ws + (size_t)(6) * (1 << 20));   // 16MB
  bf16* khb = (bf16*)(ws + (size_t)(22) * (1 << 20));  // 16MB
  bf16* vtb = (bf16*)(ws + (size_t)(38) * (1 << 20));  // 16MB
  bf16* mb16 = (bf16*)(ws + (size_t)(54) * (1 << 20)); // 16KB
  // bf16 copy of x lives in d_out's first 16MB (dead until attn writes)
  bf16* xb = (bf16*)d_out;

  cast_f32_bf16<<<2048, 256, 0, stream>>>(x, xb, NB * NS * ND);
  cast_weights<<<dim3(512, 3), 256, 0, stream>>>(Wq, Wk, Wv, wqb);
  mask_to_bf16<<<32, 256, 0, stream>>>(mask, mb16, NB * NS);
  proj_kernel<0><<<512, 256, 0, stream>>>(xb, wqb, bq, mask, qhb);
  proj_kernel<1><<<512, 256, 0, stream>>>(xb, wkb, bk, mask, khb);
  proj_kernel<2><<<512, 256, 0, stream>>>(xb, wvb, bv, mask, vtb);
  attn_kernel<<<1024, 256, 0, stream>>>(qhb, khb, vtb, mb16, out);
}

// Round 8
// 253.871 us; speedup vs baseline: 1.2223x; 1.1091x over previous
//
#include <hip/hip_runtime.h>
#include <hip/hip_bf16.h>

// MultiHeadedSelfAttention: B=4, S=2048, D=1024, H=16, W=64
//   1. cast x -> bf16 (scratch inside d_out, dead until final write)
//   2. cast Wq/Wk/Wv -> bf16 (contiguous); mask -> bf16 {0,1}
//   3. ONE fused projection launch dim3(512,3) (y=mode): 128x128 tile,
//      single-buffered 32KB LDS (m97 structure), shared swapped-MFMA hot
//      loop for all modes, XCD+L2-aware mapping. q PRESCALED by
//      (1/8)*log2(e). V masked-keys zeroed.
//   4. flash attention, 32x32 MFMA, swapped QK^T, in-register P exchange
//      (cvt_pk + permlane32_swap), raw v_exp_f32 softmax, row-sums via
//      mask-vector MFMA, XCD-aware block swizzle.
// K/V LDS tiles XOR-swizzled (elem ^ ((row&7)<<3)) via pre-swizzled global
// source columns (global_load_lds writes linearly; same involution on read).

#define NB 4
#define NS 2048
#define ND 1024
#define NH 16
#define NW 64

typedef __bf16 bf16;
typedef __bf16 bf16x2 __attribute__((ext_vector_type(2)));
typedef __bf16 bf16x4 __attribute__((ext_vector_type(4)));
typedef __bf16 bf16x8 __attribute__((ext_vector_type(8)));
typedef float f32x4 __attribute__((ext_vector_type(4)));
typedef float f32x16 __attribute__((ext_vector_type(16)));
typedef unsigned u32x4 __attribute__((ext_vector_type(4)));

__device__ __forceinline__ void gld_lds16(const void* g, void* l) {
  __builtin_amdgcn_global_load_lds(
      (const __attribute__((address_space(1))) void*)g,
      (__attribute__((address_space(3))) void*)l, 16, 0, 0);
}

__device__ __forceinline__ unsigned pack2(float lo, float hi) {
  bf16x2 t;
  t[0] = (bf16)lo;
  t[1] = (bf16)hi;
  return __builtin_bit_cast(unsigned, t);
}

__global__ void cast_f32_bf16(const float* __restrict__ src,
                              bf16* __restrict__ dst, int n) {
  int i = (blockIdx.x * blockDim.x + threadIdx.x) * 8;
  int stride = gridDim.x * blockDim.x * 8;
  for (; i < n; i += stride) {
    float4 a = *reinterpret_cast<const float4*>(src + i);
    float4 b = *reinterpret_cast<const float4*>(src + i + 4);
    bf16x8 o;
    o[0] = (bf16)a.x; o[1] = (bf16)a.y; o[2] = (bf16)a.z; o[3] = (bf16)a.w;
    o[4] = (bf16)b.x; o[5] = (bf16)b.y; o[6] = (bf16)b.z; o[7] = (bf16)b.w;
    *reinterpret_cast<bf16x8*>(dst + i) = o;
  }
}

__global__ void cast_weights(const float* __restrict__ a,
                             const float* __restrict__ b,
                             const float* __restrict__ c,
                             bf16* __restrict__ dst) {
  const int n = ND * ND;
  const int which = blockIdx.y;
  const float* src = (which == 0) ? a : ((which == 1) ? b : c);
  bf16* d = dst + (size_t)which * n;
  int i = (blockIdx.x * blockDim.x + threadIdx.x) * 8;
  float4 u = *reinterpret_cast<const float4*>(src + i);
  float4 v = *reinterpret_cast<const float4*>(src + i + 4);
  bf16x8 o;
  o[0] = (bf16)u.x; o[1] = (bf16)u.y; o[2] = (bf16)u.z; o[3] = (bf16)u.w;
  o[4] = (bf16)v.x; o[5] = (bf16)v.y; o[6] = (bf16)v.z; o[7] = (bf16)v.w;
  *reinterpret_cast<bf16x8*>(d + i) = o;
}

__global__ void mask_to_bf16(const int* __restrict__ mask,
                             bf16* __restrict__ mb, int n) {
  int i = blockIdx.x * blockDim.x + threadIdx.x;
  if (i < n) mb[i] = (bf16)(mask[i] ? 1.0f : 0.0f);
}

// ---------------- fused projection GEMM ----------------
// grid dim3(512, 3): y = mode (0=q prescaled, 1=k, 2=v^T masked).
// Shared swapped-operand hot loop: acc reg-rows = W-rows (j/w),
// lane-cols = x-rows (s). Single-buffered 32KB LDS, 2 barriers/K-step.
__global__ __launch_bounds__(256) void proj_fused(
    const bf16* __restrict__ xb,
    const bf16* __restrict__ wall,   // wq|wk|wv contiguous
    const float* __restrict__ bq,
    const float* __restrict__ bk,
    const float* __restrict__ bv,
    const int* __restrict__ mask,
    bf16* __restrict__ qh,
    bf16* __restrict__ kh,
    bf16* __restrict__ vt) {
  const int mode = blockIdx.y;
  const bf16* wmat = wall + (size_t)mode * ND * ND;
  const float* bias = (mode == 0) ? bq : ((mode == 1) ? bk : bv);

  __shared__ alignas(16) bf16 a_lds[128][64];
  __shared__ alignas(16) bf16 b_lds[128][64];

  const int tid = threadIdx.x;
  const int wave = tid >> 6;
  const int lane = tid & 63;
  const int wr = wave >> 1, wc = wave & 1;

  // XCD+L2-aware mapping (512 % 8 == 0 so blockIdx.y preserves x&7 = XCD)
  const int p = blockIdx.x;
  const int xcd = p & 7, q = p >> 3;
  const int m0 = (xcd * 8 + (q & 7)) * 128;
  const int n0 = (q >> 3) * 128;

  f32x4 acc[4][4] = {};

  const int srow = tid >> 3;
  const int scol = (tid & 7) * 8;
  const int sw_scol = scol ^ ((srow & 7) << 3);
  const int xr = (lane & 7) << 3;
  const int lr = lane & 15;
  const int g = lane >> 4;
  const int kq = g * 8;

  for (int k0 = 0; k0 < 1024; k0 += 64) {
#pragma unroll
    for (int c = 0; c < 4; ++c) {
      const int row = srow + c * 32;
      gld_lds16(xb + (size_t)(m0 + row) * 1024 + k0 + sw_scol, &a_lds[row][scol]);
      gld_lds16(wmat + (size_t)(n0 + row) * 1024 + k0 + sw_scol, &b_lds[row][scol]);
    }
    __syncthreads();
#pragma unroll
    for (int kk = 0; kk < 64; kk += 32) {
      bf16x8 af[4], bfr[4];
      const int col = (kk + kq) ^ xr;
#pragma unroll
      for (int mf = 0; mf < 4; ++mf)
        af[mf] = *reinterpret_cast<const bf16x8*>(&a_lds[wr * 64 + mf * 16 + lr][col]);
#pragma unroll
      for (int nf = 0; nf < 4; ++nf)
        bfr[nf] = *reinterpret_cast<const bf16x8*>(&b_lds[wc * 64 + nf * 16 + lr][col]);
#pragma unroll
      for (int nf = 0; nf < 4; ++nf)
#pragma unroll
        for (int mf = 0; mf < 4; ++mf)
          acc[nf][mf] = __builtin_amdgcn_mfma_f32_16x16x32_bf16(bfr[nf], af[mf], acc[nf][mf], 0, 0, 0);
    }
    __syncthreads();
  }

  if (mode == 2) {
    // vt[b][h][w][s]; lane-cols = s, reg r = w offset. 16 lanes write
    // 16 consecutive s per (nf,r) -> 32B coalesced runs.
#pragma unroll
    for (int mf = 0; mf < 4; ++mf) {
      const int i = m0 + wr * 64 + mf * 16 + lr;  // s index
      const int b = i >> 11, s = i & 2047;
      const float mskv = mask[b * NS + s] ? 1.f : 0.f;
#pragma unroll
      for (int nf = 0; nf < 4; ++nf) {
        const int j0 = n0 + wc * 64 + nf * 16 + g * 4;
        const f32x4 bj = *reinterpret_cast<const f32x4*>(&bias[j0]);
        const int h = j0 >> 6, w0 = j0 & 63;
#pragma unroll
        for (int r = 0; r < 4; ++r)
          vt[((size_t)(b * NH + h) * NW + w0 + r) * NS + s] =
              (bf16)((acc[nf][mf][r] + bj[r]) * mskv);
      }
    }
  } else {
    // q/k: [b][h][s][w], pack bf16x4 along w; q prescaled by (1/8)*log2(e)
    bf16* dst = (mode == 0) ? qh : kh;
    const float scl = (mode == 0) ? 0.18033688011112042f : 1.0f;
#pragma unroll
    for (int nf = 0; nf < 4; ++nf) {
      const int j0 = n0 + wc * 64 + nf * 16 + g * 4;
      const f32x4 bj = *reinterpret_cast<const f32x4*>(&bias[j0]);
      const int h = j0 >> 6, w0 = j0 & 63;
#pragma unroll
      for (int mf = 0; mf < 4; ++mf) {
        const int i = m0 + wr * 64 + mf * 16 + lr;
        const int b = i >> 11, s = i & 2047;
        bf16x4 pk;
#pragma unroll
        for (int r = 0; r < 4; ++r)
          pk[r] = (bf16)((acc[nf][mf][r] + bj[r]) * scl);
        *reinterpret_cast<bf16x4*>(&dst[(((size_t)(b * NH + h)) * NS + s) * NW + w0]) = pk;
      }
    }
  }
}

// ---------------- flash attention ----------------
// grid: 1024 linear blocks, XCD-swizzled: all 16 q-tiles of a head (8 heads
// per XCD) land on one XCD so K/V stay in its L2. 4 waves, 32 q-rows/wave.
__global__ __launch_bounds__(256, 4) void attn_kernel(
    const bf16* __restrict__ qh,
    const bf16* __restrict__ kh,
    const bf16* __restrict__ vt,
    const bf16* __restrict__ mb16,
    float* __restrict__ out) {
  __shared__ alignas(16) bf16 k_lds[2][64][64];
  __shared__ alignas(16) bf16 v_lds[2][64][64];  // [w][t]

  const int tid = threadIdx.x;
  const int wave = tid >> 6;
  const int lane = tid & 63;
  const int lq = lane & 31;
  const int hi = lane >> 5;
  const int xr = (lq & 7) << 3;

  const int p = blockIdx.x;
  const int w_id = (p & 7) * 128 + (p >> 3);
  const int bh = w_id >> 4;
  const int b = bh >> 4;
  const int q0 = (w_id & 15) * 128;
  const size_t headoff = (size_t)bh * NS * NW;

  bf16x8 qf[4];
  {
    const bf16* qp = qh + headoff + (size_t)(q0 + wave * 32 + lq) * NW + hi * 8;
#pragma unroll
    for (int m = 0; m < 4; ++m)
      qf[m] = *reinterpret_cast<const bf16x8*>(qp + m * 16);
  }

  f32x16 o0 = {}, o1 = {}, lt = {};
  const bf16* mp = mb16 + b * NS;

  const int srow = tid >> 3;
  const int scol = (tid & 7) * 8;
  const int sw_scol = scol ^ ((srow & 7) << 3);

#define STAGE(buf, kt)                                                          \
  {                                                                             \
    _Pragma("unroll") for (int c = 0; c < 2; ++c) {                             \
      const int row = srow + c * 32;                                            \
      gld_lds16(kh + headoff + (size_t)((kt) + row) * NW + sw_scol,             \
                &k_lds[buf][row][scol]);                                        \
      gld_lds16(vt + headoff + (size_t)row * NS + (kt) + sw_scol,               \
                &v_lds[buf][row][scol]);                                        \
    }                                                                           \
  }

#define EXPPACK(S, PA0, PA1)                                                    \
  {                                                                             \
    unsigned w_[8];                                                             \
    _Pragma("unroll") for (int j = 0; j < 8; ++j)                               \
        w_[j] = pack2(__builtin_amdgcn_exp2f(S[2 * j]),                         \
                      __builtin_amdgcn_exp2f(S[2 * j + 1]));                    \
    asm("v_permlane32_swap_b32 %0, %1" : "+v"(w_[0]), "+v"(w_[2]));             \
    asm("v_permlane32_swap_b32 %0, %1" : "+v"(w_[1]), "+v"(w_[3]));             \
    asm("v_permlane32_swap_b32 %0, %1" : "+v"(w_[4]), "+v"(w_[6]));             \
    asm("v_permlane32_swap_b32 %0, %1" : "+v"(w_[5]), "+v"(w_[7]));             \
    u32x4 u0 = {w_[0], w_[1], w_[2], w_[3]};                                    \
    u32x4 u1 = {w_[4], w_[5], w_[6], w_[7]};                                    \
    PA0 = __builtin_bit_cast(bf16x8, u0);                                       \
    PA1 = __builtin_bit_cast(bf16x8, u1);                                       \
  }

  STAGE(0, 0);
  __syncthreads();

  int cur = 0;
  for (int kt = 0; kt < NS; kt += 64) {
    if (kt + 64 < NS) STAGE(cur ^ 1, kt + 64);

    f32x16 s0 = {}, s1 = {};
    __builtin_amdgcn_s_setprio(1);
#pragma unroll
    for (int m = 0; m < 4; ++m) {
      const int col = (m * 16 + hi * 8) ^ xr;
      bf16x8 kf0 = *reinterpret_cast<const bf16x8*>(&k_lds[cur][lq][col]);
      s0 = __builtin_amdgcn_mfma_f32_32x32x16_bf16(kf0, qf[m], s0, 0, 0, 0);
      bf16x8 kf1 = *reinterpret_cast<const bf16x8*>(&k_lds[cur][32 + lq][col]);
      s1 = __builtin_amdgcn_mfma_f32_32x32x16_bf16(kf1, qf[m], s1, 0, 0, 0);
    }
    __builtin_amdgcn_s_setprio(0);

    bf16x8 pa0, pa1, pa2, pa3;
    EXPPACK(s0, pa0, pa1);
    EXPPACK(s1, pa2, pa3);

    const bf16* mpk = mp + kt + hi * 8;
    bf16x8 mf00 = *reinterpret_cast<const bf16x8*>(mpk);
    bf16x8 mf01 = *reinterpret_cast<const bf16x8*>(mpk + 16);
    bf16x8 mf10 = *reinterpret_cast<const bf16x8*>(mpk + 32);
    bf16x8 mf11 = *reinterpret_cast<const bf16x8*>(mpk + 48);

    __builtin_amdgcn_s_setprio(1);
    lt = __builtin_amdgcn_mfma_f32_32x32x16_bf16(pa0, mf00, lt, 0, 0, 0);
    lt = __builtin_amdgcn_mfma_f32_32x32x16_bf16(pa1, mf01, lt, 0, 0, 0);
    lt = __builtin_amdgcn_mfma_f32_32x32x16_bf16(pa2, mf10, lt, 0, 0, 0);
    lt = __builtin_amdgcn_mfma_f32_32x32x16_bf16(pa3, mf11, lt, 0, 0, 0);
#pragma unroll
    for (int G = 0; G < 2; ++G) {
      const bf16x8 a0 = G ? pa2 : pa0;
      const bf16x8 a1 = G ? pa3 : pa1;
      const int c0 = (G * 32 + hi * 8) ^ xr;
      const int c1 = (G * 32 + 16 + hi * 8) ^ xr;
      bf16x8 v00 = *reinterpret_cast<const bf16x8*>(&v_lds[cur][lq][c0]);
      o0 = __builtin_amdgcn_mfma_f32_32x32x16_bf16(a0, v00, o0, 0, 0, 0);
      bf16x8 v01 = *reinterpret_cast<const bf16x8*>(&v_lds[cur][lq][c1]);
      o0 = __builtin_amdgcn_mfma_f32_32x32x16_bf16(a1, v01, o0, 0, 0, 0);
      bf16x8 v10 = *reinterpret_cast<const bf16x8*>(&v_lds[cur][32 + lq][c0]);
      o1 = __builtin_amdgcn_mfma_f32_32x32x16_bf16(a0, v10, o1, 0, 0, 0);
      bf16x8 v11 = *reinterpret_cast<const bf16x8*>(&v_lds[cur][32 + lq][c1]);
      o1 = __builtin_amdgcn_mfma_f32_32x32x16_bf16(a1, v11, o1, 0, 0, 0);
    }
    __builtin_amdgcn_s_setprio(0);

    __syncthreads();
    cur ^= 1;
  }

  const int h = bh & 15;
  float* op = out + ((size_t)b * NS) * ND + h * NW;
#pragma unroll
  for (int r = 0; r < 16; ++r) {
    const int sq = q0 + wave * 32 + (r & 3) + 8 * (r >> 2) + 4 * hi;
    const float inv = 1.0f / lt[r];
    op[(size_t)sq * ND + lq] = o0[r] * inv;
    op[(size_t)sq * ND + 32 + lq] = o1[r] * inv;
  }
#undef STAGE
#undef EXPPACK
}

extern "C" void kernel_launch(void* const* d_in, const int* in_sizes, int n_in,
                              void* d_out, int out_size, void* d_ws, size_t ws_size,
                              hipStream_t stream) {
  const float* x = (const float*)d_in[0];
  const int* mask = (const int*)d_in[1];
  const float* Wq = (const float*)d_in[2];
  const float* bq = (const float*)d_in[3];
  const float* Wk = (const float*)d_in[4];
  const float* bk = (const float*)d_in[5];
  const float* Wv = (const float*)d_in[6];
  const float* bv = (const float*)d_in[7];
  float* out = (float*)d_out;

  char* ws = (char*)d_ws;
  bf16* wall = (bf16*)(ws + (size_t)(0) * (1 << 20));  // wq|wk|wv, 6MB
  bf16* qhb = (bf16*)(ws + (size_t)(6) * (1 << 20));   // 16MB
  bf16* khb = (bf16*)(ws + (size_t)(22) * (1 << 20));  // 16MB
  bf16* vtb = (bf16*)(ws + (size_t)(38) * (1 << 20));  // 16MB
  bf16* mb16 = (bf16*)(ws + (size_t)(54) * (1 << 20)); // 16KB
  // bf16 copy of x lives in d_out's first 16MB (dead until attn writes)
  bf16* xb = (bf16*)d_out;

  cast_f32_bf16<<<2048, 256, 0, stream>>>(x, xb, NB * NS * ND);
  cast_weights<<<dim3(512, 3), 256, 0, stream>>>(Wq, Wk, Wv, wall);
  mask_to_bf16<<<32, 256, 0, stream>>>(mask, mb16, NB * NS);
  proj_fused<<<dim3(512, 3), 256, 0, stream>>>(xb, wall, bq, bk, bv, mask,
                                               qhb, khb, vtb);
  attn_kernel<<<1024, 256, 0, stream>>>(qhb, khb, vtb, mb16, out);
}

// Round 10
// 249.541 us; speedup vs baseline: 1.2435x; 1.0174x over previous
//
#include <hip/hip_runtime.h>
#include <hip/hip_bf16.h>

// MultiHeadedSelfAttention: B=4, S=2048, D=1024, H=16, W=64
//   1. cast x -> bf16 (scratch inside d_out, dead until final write)
//   2. cast Wq/Wk/Wv -> bf16 (contiguous); mask -> bf16 {0,1}
//   3. ONE fused projection launch dim3(512,3) (y=mode): 128x128 tile,
//      single-buffered 32KB LDS (m97 structure), shared swapped-MFMA hot
//      loop, XCD+L2-aware mapping. q PRESCALED by (1/8)*log2(e).
//   4. flash attention: each wave owns TWO 32-row q-subtiles (64 q-rows)
//      so every K/V LDS fragment read feeds 2x the MFMA work (LDS was the
//      co-limiting pipe at 1 subtile/wave). 4 waves/block = 256 q-rows,
//      grid 512 = 2 blocks/CU. Swapped QK^T, in-register P exchange
//      (cvt_pk + permlane32_swap), raw v_exp_f32, row-sums via mask-MFMA,
//      XCD-aware swizzle (8 heads/XCD -> K/V L2-resident, 24.6MB fetch).
// K/V LDS tiles XOR-swizzled (elem ^ ((row&7)<<3)) via pre-swizzled global
// source columns (global_load_lds writes linearly; same involution on read).

#define NB 4
#define NS 2048
#define ND 1024
#define NH 16
#define NW 64

typedef __bf16 bf16;
typedef __bf16 bf16x2 __attribute__((ext_vector_type(2)));
typedef __bf16 bf16x4 __attribute__((ext_vector_type(4)));
typedef __bf16 bf16x8 __attribute__((ext_vector_type(8)));
typedef float f32x4 __attribute__((ext_vector_type(4)));
typedef float f32x16 __attribute__((ext_vector_type(16)));
typedef unsigned u32x4 __attribute__((ext_vector_type(4)));

__device__ __forceinline__ void gld_lds16(const void* g, void* l) {
  __builtin_amdgcn_global_load_lds(
      (const __attribute__((address_space(1))) void*)g,
      (__attribute__((address_space(3))) void*)l, 16, 0, 0);
}

__device__ __forceinline__ unsigned pack2(float lo, float hi) {
  bf16x2 t;
  t[0] = (bf16)lo;
  t[1] = (bf16)hi;
  return __builtin_bit_cast(unsigned, t);
}

__global__ void cast_f32_bf16(const float* __restrict__ src,
                              bf16* __restrict__ dst, int n) {
  int i = (blockIdx.x * blockDim.x + threadIdx.x) * 8;
  int stride = gridDim.x * blockDim.x * 8;
  for (; i < n; i += stride) {
    float4 a = *reinterpret_cast<const float4*>(src + i);
    float4 b = *reinterpret_cast<const float4*>(src + i + 4);
    bf16x8 o;
    o[0] = (bf16)a.x; o[1] = (bf16)a.y; o[2] = (bf16)a.z; o[3] = (bf16)a.w;
    o[4] = (bf16)b.x; o[5] = (bf16)b.y; o[6] = (bf16)b.z; o[7] = (bf16)b.w;
    *reinterpret_cast<bf16x8*>(dst + i) = o;
  }
}

__global__ void cast_weights(const float* __restrict__ a,
                             const float* __restrict__ b,
                             const float* __restrict__ c,
                             bf16* __restrict__ dst) {
  const int n = ND * ND;
  const int which = blockIdx.y;
  const float* src = (which == 0) ? a : ((which == 1) ? b : c);
  bf16* d = dst + (size_t)which * n;
  int i = (blockIdx.x * blockDim.x + threadIdx.x) * 8;
  float4 u = *reinterpret_cast<const float4*>(src + i);
  float4 v = *reinterpret_cast<const float4*>(src + i + 4);
  bf16x8 o;
  o[0] = (bf16)u.x; o[1] = (bf16)u.y; o[2] = (bf16)u.z; o[3] = (bf16)u.w;
  o[4] = (bf16)v.x; o[5] = (bf16)v.y; o[6] = (bf16)v.z; o[7] = (bf16)v.w;
  *reinterpret_cast<bf16x8*>(d + i) = o;
}

__global__ void mask_to_bf16(const int* __restrict__ mask,
                             bf16* __restrict__ mb, int n) {
  int i = blockIdx.x * blockDim.x + threadIdx.x;
  if (i < n) mb[i] = (bf16)(mask[i] ? 1.0f : 0.0f);
}

// ---------------- fused projection GEMM ----------------
__global__ __launch_bounds__(256) void proj_fused(
    const bf16* __restrict__ xb,
    const bf16* __restrict__ wall,
    const float* __restrict__ bq,
    const float* __restrict__ bk,
    const float* __restrict__ bv,
    const int* __restrict__ mask,
    bf16* __restrict__ qh,
    bf16* __restrict__ kh,
    bf16* __restrict__ vt) {
  const int mode = blockIdx.y;
  const bf16* wmat = wall + (size_t)mode * ND * ND;
  const float* bias = (mode == 0) ? bq : ((mode == 1) ? bk : bv);

  __shared__ alignas(16) bf16 a_lds[128][64];
  __shared__ alignas(16) bf16 b_lds[128][64];

  const int tid = threadIdx.x;
  const int wave = tid >> 6;
  const int lane = tid & 63;
  const int wr = wave >> 1, wc = wave & 1;

  const int p = blockIdx.x;
  const int xcd = p & 7, q = p >> 3;
  const int m0 = (xcd * 8 + (q & 7)) * 128;
  const int n0 = (q >> 3) * 128;

  f32x4 acc[4][4] = {};

  const int srow = tid >> 3;
  const int scol = (tid & 7) * 8;
  const int sw_scol = scol ^ ((srow & 7) << 3);
  const int xr = (lane & 7) << 3;
  const int lr = lane & 15;
  const int g = lane >> 4;
  const int kq = g * 8;

  for (int k0 = 0; k0 < 1024; k0 += 64) {
#pragma unroll
    for (int c = 0; c < 4; ++c) {
      const int row = srow + c * 32;
      gld_lds16(xb + (size_t)(m0 + row) * 1024 + k0 + sw_scol, &a_lds[row][scol]);
      gld_lds16(wmat + (size_t)(n0 + row) * 1024 + k0 + sw_scol, &b_lds[row][scol]);
    }
    __syncthreads();
#pragma unroll
    for (int kk = 0; kk < 64; kk += 32) {
      bf16x8 af[4], bfr[4];
      const int col = (kk + kq) ^ xr;
#pragma unroll
      for (int mf = 0; mf < 4; ++mf)
        af[mf] = *reinterpret_cast<const bf16x8*>(&a_lds[wr * 64 + mf * 16 + lr][col]);
#pragma unroll
      for (int nf = 0; nf < 4; ++nf)
        bfr[nf] = *reinterpret_cast<const bf16x8*>(&b_lds[wc * 64 + nf * 16 + lr][col]);
#pragma unroll
      for (int nf = 0; nf < 4; ++nf)
#pragma unroll
        for (int mf = 0; mf < 4; ++mf)
          acc[nf][mf] = __builtin_amdgcn_mfma_f32_16x16x32_bf16(bfr[nf], af[mf], acc[nf][mf], 0, 0, 0);
    }
    __syncthreads();
  }

  if (mode == 2) {
#pragma unroll
    for (int mf = 0; mf < 4; ++mf) {
      const int i = m0 + wr * 64 + mf * 16 + lr;
      const int b = i >> 11, s = i & 2047;
      const float mskv = mask[b * NS + s] ? 1.f : 0.f;
#pragma unroll
      for (int nf = 0; nf < 4; ++nf) {
        const int j0 = n0 + wc * 64 + nf * 16 + g * 4;
        const f32x4 bj = *reinterpret_cast<const f32x4*>(&bias[j0]);
        const int h = j0 >> 6, w0 = j0 & 63;
#pragma unroll
        for (int r = 0; r < 4; ++r)
          vt[((size_t)(b * NH + h) * NW + w0 + r) * NS + s] =
              (bf16)((acc[nf][mf][r] + bj[r]) * mskv);
      }
    }
  } else {
    bf16* dst = (mode == 0) ? qh : kh;
    const float scl = (mode == 0) ? 0.18033688011112042f : 1.0f;
#pragma unroll
    for (int nf = 0; nf < 4; ++nf) {
      const int j0 = n0 + wc * 64 + nf * 16 + g * 4;
      const f32x4 bj = *reinterpret_cast<const f32x4*>(&bias[j0]);
      const int h = j0 >> 6, w0 = j0 & 63;
#pragma unroll
      for (int mf = 0; mf < 4; ++mf) {
        const int i = m0 + wr * 64 + mf * 16 + lr;
        const int b = i >> 11, s = i & 2047;
        bf16x4 pk;
#pragma unroll
        for (int r = 0; r < 4; ++r)
          pk[r] = (bf16)((acc[nf][mf][r] + bj[r]) * scl);
        *reinterpret_cast<bf16x4*>(&dst[(((size_t)(b * NH + h)) * NS + s) * NW + w0]) = pk;
      }
    }
  }
}

// ---------------- flash attention ----------------
// grid: 512 blocks (XCD-swizzled, 8 heads/XCD). 4 waves/block; each wave
// owns q-subtiles A (q0+wave*32) and B (q0+128+wave*32) -> 256 rows/block.
__global__ __launch_bounds__(256, 2) void attn_kernel(
    const bf16* __restrict__ qh,
    const bf16* __restrict__ kh,
    const bf16* __restrict__ vt,
    const bf16* __restrict__ mb16,
    float* __restrict__ out) {
  __shared__ alignas(16) bf16 k_lds[2][64][64];
  __shared__ alignas(16) bf16 v_lds[2][64][64];  // [w][t]

  const int tid = threadIdx.x;
  const int wave = tid >> 6;
  const int lane = tid & 63;
  const int lq = lane & 31;
  const int hi = lane >> 5;
  const int xr = (lq & 7) << 3;

  const int p = blockIdx.x;                      // 512 blocks
  const int w_id = (p & 7) * 64 + (p >> 3);      // bijective, 64 ids/XCD
  const int bh = w_id >> 3;                      // 8 heads per XCD
  const int b = bh >> 4;
  const int q0 = (w_id & 7) * 256;
  const size_t headoff = (size_t)bh * NS * NW;

  bf16x8 qfa[4], qfb[4];
  {
    const bf16* qp = qh + headoff + (size_t)(q0 + wave * 32 + lq) * NW + hi * 8;
#pragma unroll
    for (int m = 0; m < 4; ++m) {
      qfa[m] = *reinterpret_cast<const bf16x8*>(qp + m * 16);
      qfb[m] = *reinterpret_cast<const bf16x8*>(qp + 128 * NW + m * 16);
    }
  }

  f32x16 o0a = {}, o1a = {}, o0b = {}, o1b = {}, lta = {}, ltb = {};
  const f32x16 kZ = {};
  const bf16* mp = mb16 + b * NS;

  const int srow = tid >> 3;
  const int scol = (tid & 7) * 8;
  const int sw_scol = scol ^ ((srow & 7) << 3);

#define STAGE(buf, kt)                                                          \
  {                                                                             \
    _Pragma("unroll") for (int c = 0; c < 2; ++c) {                             \
      const int row = srow + c * 32;                                            \
      gld_lds16(kh + headoff + (size_t)((kt) + row) * NW + sw_scol,             \
                &k_lds[buf][row][scol]);                                        \
      gld_lds16(vt + headoff + (size_t)row * NS + (kt) + sw_scol,               \
                &v_lds[buf][row][scol]);                                        \
    }                                                                           \
  }

#define EXPPACK(S, PA0, PA1)                                                    \
  {                                                                             \
    unsigned w_[8];                                                             \
    _Pragma("unroll") for (int j = 0; j < 8; ++j)                               \
        w_[j] = pack2(__builtin_amdgcn_exp2f(S[2 * j]),                         \
                      __builtin_amdgcn_exp2f(S[2 * j + 1]));                    \
    asm("v_permlane32_swap_b32 %0, %1" : "+v"(w_[0]), "+v"(w_[2]));             \
    asm("v_permlane32_swap_b32 %0, %1" : "+v"(w_[1]), "+v"(w_[3]));             \
    asm("v_permlane32_swap_b32 %0, %1" : "+v"(w_[4]), "+v"(w_[6]));             \
    asm("v_permlane32_swap_b32 %0, %1" : "+v"(w_[5]), "+v"(w_[7]));             \
    u32x4 u0 = {w_[0], w_[1], w_[2], w_[3]};                                    \
    u32x4 u1 = {w_[4], w_[5], w_[6], w_[7]};                                    \
    PA0 = __builtin_bit_cast(bf16x8, u0);                                       \
    PA1 = __builtin_bit_cast(bf16x8, u1);                                       \
  }

  STAGE(0, 0);
  __syncthreads();

  int cur = 0;
  for (int kt = 0; kt < NS; kt += 64) {
    if (kt + 64 < NS) STAGE(cur ^ 1, kt + 64);

    // ---- QK^T: 8 shared K-reads feed both q-subtiles (16 MFMA) ----
    f32x16 s0a, s1a, s0b, s1b;
    __builtin_amdgcn_s_setprio(1);
#pragma unroll
    for (int m = 0; m < 4; ++m) {
      const int col = (m * 16 + hi * 8) ^ xr;
      bf16x8 kf0 = *reinterpret_cast<const bf16x8*>(&k_lds[cur][lq][col]);
      bf16x8 kf1 = *reinterpret_cast<const bf16x8*>(&k_lds[cur][32 + lq][col]);
      s0a = __builtin_amdgcn_mfma_f32_32x32x16_bf16(kf0, qfa[m], m ? s0a : kZ, 0, 0, 0);
      s1a = __builtin_amdgcn_mfma_f32_32x32x16_bf16(kf1, qfa[m], m ? s1a : kZ, 0, 0, 0);
      s0b = __builtin_amdgcn_mfma_f32_32x32x16_bf16(kf0, qfb[m], m ? s0b : kZ, 0, 0, 0);
      s1b = __builtin_amdgcn_mfma_f32_32x32x16_bf16(kf1, qfb[m], m ? s1b : kZ, 0, 0, 0);
    }
    __builtin_amdgcn_s_setprio(0);

    // ---- softmax numerators, in-register ----
    bf16x8 pa0, pa1, pa2, pa3, pb0, pb1, pb2, pb3;
    EXPPACK(s0a, pa0, pa1);
    EXPPACK(s1a, pa2, pa3);
    EXPPACK(s0b, pb0, pb1);
    EXPPACK(s1b, pb2, pb3);

    const bf16* mpk = mp + kt + hi * 8;
    bf16x8 mf00 = *reinterpret_cast<const bf16x8*>(mpk);
    bf16x8 mf01 = *reinterpret_cast<const bf16x8*>(mpk + 16);
    bf16x8 mf10 = *reinterpret_cast<const bf16x8*>(mpk + 32);
    bf16x8 mf11 = *reinterpret_cast<const bf16x8*>(mpk + 48);

    // ---- row-sums (mask-MFMA) + PV: 8 shared V-reads feed 24 MFMA ----
    __builtin_amdgcn_s_setprio(1);
    lta = __builtin_amdgcn_mfma_f32_32x32x16_bf16(pa0, mf00, lta, 0, 0, 0);
    lta = __builtin_amdgcn_mfma_f32_32x32x16_bf16(pa1, mf01, lta, 0, 0, 0);
    lta = __builtin_amdgcn_mfma_f32_32x32x16_bf16(pa2, mf10, lta, 0, 0, 0);
    lta = __builtin_amdgcn_mfma_f32_32x32x16_bf16(pa3, mf11, lta, 0, 0, 0);
    ltb = __builtin_amdgcn_mfma_f32_32x32x16_bf16(pb0, mf00, ltb, 0, 0, 0);
    ltb = __builtin_amdgcn_mfma_f32_32x32x16_bf16(pb1, mf01, ltb, 0, 0, 0);
    ltb = __builtin_amdgcn_mfma_f32_32x32x16_bf16(pb2, mf10, ltb, 0, 0, 0);
    ltb = __builtin_amdgcn_mfma_f32_32x32x16_bf16(pb3, mf11, ltb, 0, 0, 0);
#pragma unroll
    for (int G = 0; G < 2; ++G) {
      const bf16x8 a0 = G ? pa2 : pa0;
      const bf16x8 a1 = G ? pa3 : pa1;
      const bf16x8 b0 = G ? pb2 : pb0;
      const bf16x8 b1 = G ? pb3 : pb1;
      const int c0 = (G * 32 + hi * 8) ^ xr;
      const int c1 = (G * 32 + 16 + hi * 8) ^ xr;
      bf16x8 v00 = *reinterpret_cast<const bf16x8*>(&v_lds[cur][lq][c0]);
      bf16x8 v01 = *reinterpret_cast<const bf16x8*>(&v_lds[cur][lq][c1]);
      bf16x8 v10 = *reinterpret_cast<const bf16x8*>(&v_lds[cur][32 + lq][c0]);
      bf16x8 v11 = *reinterpret_cast<const bf16x8*>(&v_lds[cur][32 + lq][c1]);
      o0a = __builtin_amdgcn_mfma_f32_32x32x16_bf16(a0, v00, o0a, 0, 0, 0);
      o0a = __builtin_amdgcn_mfma_f32_32x32x16_bf16(a1, v01, o0a, 0, 0, 0);
      o1a = __builtin_amdgcn_mfma_f32_32x32x16_bf16(a0, v10, o1a, 0, 0, 0);
      o1a = __builtin_amdgcn_mfma_f32_32x32x16_bf16(a1, v11, o1a, 0, 0, 0);
      o0b = __builtin_amdgcn_mfma_f32_32x32x16_bf16(b0, v00, o0b, 0, 0, 0);
      o0b = __builtin_amdgcn_mfma_f32_32x32x16_bf16(b1, v01, o0b, 0, 0, 0);
      o1b = __builtin_amdgcn_mfma_f32_32x32x16_bf16(b0, v10, o1b, 0, 0, 0);
      o1b = __builtin_amdgcn_mfma_f32_32x32x16_bf16(b1, v11, o1b, 0, 0, 0);
    }
    __builtin_amdgcn_s_setprio(0);

    __syncthreads();
    cur ^= 1;
  }

  const int h = bh & 15;
  float* op = out + ((size_t)b * NS) * ND + h * NW;
#pragma unroll
  for (int r = 0; r < 16; ++r) {
    const int rr = (r & 3) + 8 * (r >> 2) + 4 * hi;
    const int sqa = q0 + wave * 32 + rr;
    const int sqb = sqa + 128;
    const float inva = 1.0f / lta[r];
    const float invb = 1.0f / ltb[r];
    op[(size_t)sqa * ND + lq] = o0a[r] * inva;
    op[(size_t)sqa * ND + 32 + lq] = o1a[r] * inva;
    op[(size_t)sqb * ND + lq] = o0b[r] * invb;
    op[(size_t)sqb * ND + 32 + lq] = o1b[r] * invb;
  }
#undef STAGE
#undef EXPPACK
}

extern "C" void kernel_launch(void* const* d_in, const int* in_sizes, int n_in,
                              void* d_out, int out_size, void* d_ws, size_t ws_size,
                              hipStream_t stream) {
  const float* x = (const float*)d_in[0];
  const int* mask = (const int*)d_in[1];
  const float* Wq = (const float*)d_in[2];
  const float* bq = (const float*)d_in[3];
  const float* Wk = (const float*)d_in[4];
  const float* bk = (const float*)d_in[5];
  const float* Wv = (const float*)d_in[6];
  const float* bv = (const float*)d_in[7];
  float* out = (float*)d_out;

  char* ws = (char*)d_ws;
  bf16* wall = (bf16*)(ws + (size_t)(0) * (1 << 20));  // wq|wk|wv, 6MB
  bf16* qhb = (bf16*)(ws + (size_t)(6) * (1 << 20));   // 16MB
  bf16* khb = (bf16*)(ws + (size_t)(22) * (1 << 20));  // 16MB
  bf16* vtb = (bf16*)(ws + (size_t)(38) * (1 << 20));  // 16MB
  bf16* mb16 = (bf16*)(ws + (size_t)(54) * (1 << 20)); // 16KB
  // bf16 copy of x lives in d_out's first 16MB (dead until attn writes)
  bf16* xb = (bf16*)d_out;

  cast_f32_bf16<<<2048, 256, 0, stream>>>(x, xb, NB * NS * ND);
  cast_weights<<<dim3(512, 3), 256, 0, stream>>>(Wq, Wk, Wv, wall);
  mask_to_bf16<<<32, 256, 0, stream>>>(mask, mb16, NB * NS);
  proj_fused<<<dim3(512, 3), 256, 0, stream>>>(xb, wall, bq, bk, bv, mask,
                                               qhb, khb, vtb);
  attn_kernel<<<512, 256, 0, stream>>>(qhb, khb, vtb, mb16, out);
}